// Round 3
// baseline (1840.881 us; speedup 1.0000x reference)
//
#include <hip/hip_runtime.h>
#include <hip/hip_bf16.h>

// Problem: T=512, B=64, N=256, H=64, D=128, P=64.
// Stage 1: x2n = input(32768x128) @ W2n^T(128x256) + b2n          (gemm_xwT)
// Stage 2: 16384 independent LSTM cells scanned over 512 steps    (lstm_scan)
// Stage 3: out = ON(32768x256) @ Wout^T(256x64) + bout            (gemm_xwT)
// Workspace: x2n 32MB + ON 32MB = 64MB of d_ws.
//
// Scan structure (swapped-operand MFMA, 2-wave split for 2 waves/SIMD):
//   gates^T = [W_hh | w_ih,bias slices] @ [h ; x,1]^T  per 16-cell group.
//   Wave w of each 128-thread block owns gate tiles nt with nt&3 in
//   {2w,2w+1} (j in [32w,32w+32)) over full K: 8 ext + 32 W_hh MFMAs.
//   D-layout puts gates of cell (lane&15) in one lane; produced
//   h[c15][q*16+4*g4+e] is exactly B-fragment slice ks=q, so each wave
//   keeps its own 2 h fragments in registers and exchanges only the
//   partner's 2 via a double-buffered LDS slot (1 barrier/step).
//   g_t = wg.h reduction is split: wave1 parks its partial in a 4-deep
//   LDS ring; wave0 reads it 2 steps later (gain_t = g_{t-2} slack);
//   ON[0] (needs g_0) is stored at t==2 with the same gain value as ON[2].

typedef __attribute__((ext_vector_type(4))) float f32x4;
typedef __attribute__((ext_vector_type(4))) short s16x4;
typedef __attribute__((ext_vector_type(8))) short s16x8;

__device__ inline short bf16r(float f) {            // round-to-nearest-even bf16
    unsigned u = __builtin_bit_cast(unsigned, f);
    u += 0x7fffu + ((u >> 16) & 1u);
    return (short)(u >> 16);
}
__device__ inline float bf2f(short s) {
    unsigned u = ((unsigned)(unsigned short)s) << 16;
    return __builtin_bit_cast(float, u);
}
__device__ inline float sigf(float x) {             // 1/(1+e^-x)
    return __builtin_amdgcn_rcpf(1.f + __builtin_amdgcn_exp2f(x * -1.4426950408889634f));
}
__device__ inline float tanh_fast(float x) {        // 1 - 2/(e^{2x}+1)
    return 1.f - 2.f * __builtin_amdgcn_rcpf(1.f + __builtin_amdgcn_exp2f(x * 2.885390081777927f));
}

#if __has_builtin(__builtin_amdgcn_mfma_f32_16x16x16bf16_1k)
#define HAVE_MFMA16 1
__device__ inline f32x4 mfma16(s16x4 a, s16x4 b, f32x4 c) {
    return __builtin_amdgcn_mfma_f32_16x16x16bf16_1k(a, b, c, 0, 0, 0);
}
#else
#define HAVE_MFMA16 0
__device__ inline s16x8 cat8(s16x4 a, s16x4 b) {
    s16x8 r;
    r[0]=a[0]; r[1]=a[1]; r[2]=a[2]; r[3]=a[3];
    r[4]=b[0]; r[5]=b[1]; r[6]=b[2]; r[7]=b[3];
    return r;
}
#endif

// ---------------------------------------------------------------------------
// Generic fp32 GEMM: Out(MxN) = X(MxK) @ Wt(NxK)^T + bias(N).  M%64==0,
// N%64==0, K%32==0.  grid = (M/64, N/64), block = 256.
// ---------------------------------------------------------------------------
__global__ __launch_bounds__(256) void gemm_xwT(
    const float* __restrict__ X, const float* __restrict__ Wt,
    const float* __restrict__ bias, float* __restrict__ Out,
    int N, int K)
{
    __shared__ float Xs[32][68];
    __shared__ float Ws[32][68];
    const int tid = threadIdx.x;
    const int tx = tid & 15, ty = tid >> 4;
    const int m0 = blockIdx.x * 64, n0 = blockIdx.y * 64;
    const int kq = tid & 7, mr = tid >> 3;

    float acc[4][4];
#pragma unroll
    for (int i = 0; i < 4; ++i)
#pragma unroll
        for (int j = 0; j < 4; ++j) acc[i][j] = 0.f;

    for (int kc = 0; kc < K; kc += 32) {
#pragma unroll
        for (int rr = 0; rr < 2; ++rr) {
            const int m = mr + rr * 32;
            f32x4 xv = *(const f32x4*)(X + (size_t)(m0 + m) * K + kc + kq * 4);
            f32x4 wv = *(const f32x4*)(Wt + (size_t)(n0 + m) * K + kc + kq * 4);
#pragma unroll
            for (int j = 0; j < 4; ++j) { Xs[kq*4 + j][m] = xv[j]; Ws[kq*4 + j][m] = wv[j]; }
        }
        __syncthreads();
#pragma unroll
        for (int k = 0; k < 32; ++k) {
            f32x4 a = *(const f32x4*)&Xs[k][ty * 4];
            f32x4 b = *(const f32x4*)&Ws[k][tx * 4];
#pragma unroll
            for (int i = 0; i < 4; ++i)
#pragma unroll
                for (int j = 0; j < 4; ++j)
                    acc[i][j] = __builtin_fmaf(a[i], b[j], acc[i][j]);
        }
        __syncthreads();
    }
    f32x4 bv = *(const f32x4*)(bias + n0 + tx * 4);
#pragma unroll
    for (int i = 0; i < 4; ++i) {
        f32x4 o;
#pragma unroll
        for (int j = 0; j < 4; ++j) o[j] = acc[i][j] + bv[j];
        *(f32x4*)(Out + (size_t)(m0 + ty * 4 + i) * N + n0 + tx * 4) = o;
    }
}

// ---------------------------------------------------------------------------
// Recurrent scan, 2-wave split.  1024 blocks x 128 threads; the block's 16
// cells (cell = cellbase + (lane&15)) are computed jointly by 2 waves.
//
// MFMA layouts (16x16x16 bf16 family), lane l, c15=l&15, g4=l>>4:
//   A: lane holds A[c15][16ks + 4*g4 + e]     (A row = gate nt*16 + c15)
//   B: lane holds B[16ks + 4*g4 + e][c15]
//   D: lane reg e holds D[4*g4 + e][c15]      (gate nt*16 + 4*g4 + e)
//
// Wave w: local tile lt=0..7 -> q = 2w+(lt&1), type = lt>>1, nt = type*4+q.
// Element (ql,e): j = (2w+ql)*16 + 4*g4 + e;  i=acc[ql], f=acc[2+ql],
// g=acc[4+ql], o=acc[6+ql].  New h -> B-fragment ks = 2w+ql.
// ---------------------------------------------------------------------------
__global__ __launch_bounds__(128, 2) void lstm_scan(
    const float* __restrict__ x2n,   // [512][16384]
    const float* __restrict__ W_hh,  // [256][64]
    const float* __restrict__ w_ih,  // [256]
    const float* __restrict__ b_ih,  // [256]
    const float* __restrict__ b_hh,  // [256]
    const float* __restrict__ wg,    // [64]
    const float* __restrict__ bg,    // [1]
    float* __restrict__ ON)          // [512][16384]
{
    __shared__ short hbuf[2][4][64][4];   // [parity][ks][lane][4] bf16, 4KB
    __shared__ float gbuf[4][16];         // wave1 g-partial ring [t&3][c15]

    const int tid = threadIdx.x;
    const int w = tid >> 6;               // wave id 0/1
    const int lane = tid & 63;
    const int c15 = lane & 15, g4 = lane >> 4;
    const int cellbase = blockIdx.x * 16;
    const int q0 = 2 * w;                 // this wave's first q / ks
    const int ko = 2 - q0;                // partner's first ks

    // A fragments of W_hh for this wave's 8 tiles (full K)
    s16x4 afw[4][8];
#pragma unroll
    for (int lt = 0; lt < 8; ++lt) {
        const int nt = (lt >> 1) * 4 + q0 + (lt & 1);
        const float* wrow = W_hh + (size_t)(nt * 16 + c15) * 64;
#pragma unroll
        for (int ks = 0; ks < 4; ++ks) {
            f32x4 wv = *(const f32x4*)(wrow + ks * 16 + g4 * 4);
            s16x4 bb;
#pragma unroll
            for (int e = 0; e < 4; ++e) bb[e] = bf16r(wv[e]);
            afw[ks][lt] = bb;
        }
    }

    // Extension slice A rows: paired with B-ext (xh, xl, xh, 1 | 1).
    s16x4 afx[8];
#pragma unroll
    for (int lt = 0; lt < 8; ++lt) {
        const int nt = (lt >> 1) * 4 + q0 + (lt & 1);
        const int g = nt * 16 + c15;
        const float wi = w_ih[g];
        const float bs = b_ih[g] + b_hh[g];
        const short wh = bf16r(wi);
        const short wl = bf16r(wi - bf2f(wh));
        const short bh_ = bf16r(bs);
        const short bl_ = bf16r(bs - bf2f(bh_));
        s16x4 v = (s16x4){0, 0, 0, 0};
        if (g4 == 0) { v[0] = wh; v[1] = wh; v[2] = wl; v[3] = bh_; }
        else if (g4 == 1) { v[0] = bl_; }
        afx[lt] = v;
    }

    // wg slices for this wave's elements: wg_l[ql][e] = wg[(q0+ql)*16+4g4+e]
    f32x4 wg_l[2];
#pragma unroll
    for (int ql = 0; ql < 2; ++ql)
        wg_l[ql] = *(const f32x4*)(wg + (q0 + ql) * 16 + g4 * 4);
    const float bg0 = bg[0];
    const short one_bf = (short)0x3F80;

    f32x4 cst[2];
    s16x4 bown[2];                        // this wave's h B-fragments
#pragma unroll
    for (int ql = 0; ql < 2; ++ql) {
        cst[ql] = (f32x4){0.f, 0.f, 0.f, 0.f};
        bown[ql] = (s16x4){0, 0, 0, 0};
        *(s16x4*)&hbuf[0][q0 + ql][lane][0] = (s16x4){0, 0, 0, 0};
    }
    __syncthreads();

    float xs = x2n[cellbase + c15];       // prefetched x for t=0
    float gp1 = 0.f, gp2 = 0.f, sp0 = 0.f;

    for (int t = 0; t < 512; ++t) {
        const int p = t & 1;

        // partner h fragments (written end of t-1, barrier passed)
        s16x4 bh[4];
        bh[ko]     = *(const s16x4*)&hbuf[p][ko][lane][0];
        bh[ko + 1] = *(const s16x4*)&hbuf[p][ko + 1][lane][0];
        bh[q0]     = bown[0];
        bh[q0 + 1] = bown[1];

        // B extension fragment from x (hi/lo bf16 split)
        const float xs_cur = xs;
        const short xh = bf16r(xs_cur);
        const short xl = bf16r(xs_cur - bf2f(xh));
        s16x4 bx = (s16x4){0, 0, 0, 0};
        if (g4 == 0) { bx[0] = xh; bx[1] = xl; bx[2] = xh; bx[3] = one_bf; }
        else if (g4 == 1) { bx[0] = one_bf; }
        if (t < 511) xs = x2n[(size_t)(t + 1) * 16384 + cellbase + c15];

        // gates for this wave's 8 tiles: ext + 4 K-slices
        f32x4 acc[8];
        const f32x4 zero4 = (f32x4){0.f, 0.f, 0.f, 0.f};
#if HAVE_MFMA16
#pragma unroll
        for (int lt = 0; lt < 8; ++lt) acc[lt] = mfma16(afx[lt], bx, zero4);
#pragma unroll
        for (int ks = 0; ks < 4; ++ks)
#pragma unroll
            for (int lt = 0; lt < 8; ++lt)
                acc[lt] = mfma16(afw[ks][lt], bh[ks], acc[lt]);
#else
        {
            const s16x4 z4 = (s16x4){0, 0, 0, 0};
            s16x8 bx8 = cat8(bx, z4);
            s16x8 b01 = cat8(bh[0], bh[1]);
            s16x8 b23 = cat8(bh[2], bh[3]);
#pragma unroll
            for (int lt = 0; lt < 8; ++lt) {
                acc[lt] = __builtin_amdgcn_mfma_f32_16x16x32_bf16(cat8(afx[lt], z4), bx8, zero4, 0, 0, 0);
                acc[lt] = __builtin_amdgcn_mfma_f32_16x16x32_bf16(cat8(afw[0][lt], afw[1][lt]), b01, acc[lt], 0, 0, 0);
                acc[lt] = __builtin_amdgcn_mfma_f32_16x16x32_bf16(cat8(afw[2][lt], afw[3][lt]), b23, acc[lt], 0, 0, 0);
            }
        }
#endif

        // nonlinearities for this wave's 8 elements
        f32x4 hvf[2];
#pragma unroll
        for (int ql = 0; ql < 2; ++ql) {
            f32x4 cn, hn;
#pragma unroll
            for (int e = 0; e < 4; ++e) {
                const float iv = acc[ql][e], fv = acc[2 + ql][e];
                const float gv = acc[4 + ql][e], ov = acc[6 + ql][e];
                const float c2 = sigf(fv) * cst[ql][e] + sigf(iv) * tanh_fast(gv);
                cn[e] = c2;
                hn[e] = sigf(ov) * tanh_fast(c2);
            }
            cst[ql] = cn;
            hvf[ql] = hn;
        }

        // own next-step B fragments: keep in regs + publish to partner
#pragma unroll
        for (int ql = 0; ql < 2; ++ql) {
            s16x4 b;
#pragma unroll
            for (int e = 0; e < 4; ++e) b[e] = bf16r(hvf[ql][e]);
            bown[ql] = b;
            *(s16x4*)&hbuf[p ^ 1][q0 + ql][lane][0] = b;
        }

        // g_t partial over this wave's j-half, reduced across g4 groups
        float gpart = 0.f;
#pragma unroll
        for (int ql = 0; ql < 2; ++ql)
#pragma unroll
            for (int e = 0; e < 4; ++e)
                gpart = __builtin_fmaf(hvf[ql][e], wg_l[ql][e], gpart);
        gpart += __shfl_xor(gpart, 16, 64);
        gpart += __shfl_xor(gpart, 32, 64);

        if (w == 1) {
            if (g4 == 0) gbuf[t & 3][c15] = gpart;   // park partial for wave0
        } else {
            // softplus(x-1)
            const float x1 = xs_cur - 1.f;
            const float sp = fmaxf(x1, 0.f) +
                0.6931471805599453f * __builtin_amdgcn_logf(
                    1.f + __builtin_amdgcn_exp2f(-1.4426950408889634f * fabsf(x1)));
            if (t == 0) {
                sp0 = sp;                            // ON[0] deferred to t==2
            } else if (t == 1) {
                if (g4 == 0) ON[(size_t)16384 + cellbase + c15] = sp;  // gain=1
            } else {
                const float gain = gp2 + gbuf[(t - 2) & 3][c15] + bg0; // g_{t-2}
                if (g4 == 0) {
                    ON[(size_t)t * 16384 + cellbase + c15] = gain * sp;
                    if (t == 2) ON[cellbase + c15] = gain * sp0;       // g_0 too
                }
            }
            gp2 = gp1;
            gp1 = gpart;
        }

        __syncthreads();   // h(t+1 parity) + gbuf visible for next step
    }
}

extern "C" void kernel_launch(void* const* d_in, const int* in_sizes, int n_in,
                              void* d_out, int out_size, void* d_ws, size_t ws_size,
                              hipStream_t stream)
{
    const float* input = (const float*)d_in[0];   // [512][64][128]
    const float* W2n   = (const float*)d_in[1];   // [256][128]
    const float* b2n   = (const float*)d_in[2];   // [256]
    const float* W_ih  = (const float*)d_in[3];   // [256] (4H x 1)
    const float* W_hh  = (const float*)d_in[4];   // [256][64]
    const float* b_ih  = (const float*)d_in[5];   // [256]
    const float* b_hh  = (const float*)d_in[6];   // [256]
    const float* Wg    = (const float*)d_in[7];   // [64]  (1 x H)
    const float* bg    = (const float*)d_in[8];   // [1]
    const float* Wout  = (const float*)d_in[9];   // [64][256]
    const float* bout  = (const float*)d_in[10];  // [64]

    float* x2n = (float*)d_ws;                          // 512*16384 f32 = 32MB
    float* ON  = x2n + (size_t)512 * 16384;             // another 32MB

    // Stage 1: x2n = input @ W2n^T + b2n   (M=32768, N=256, K=128)
    gemm_xwT<<<dim3(512, 4), 256, 0, stream>>>(input, W2n, b2n, x2n, 256, 128);

    // Stage 2: recurrent scan -> ON
    lstm_scan<<<1024, 128, 0, stream>>>(x2n, W_hh, W_ih, b_ih, b_hh, Wg, bg, ON);

    // Stage 3: out = ON @ Wout^T + bout    (M=32768, N=64, K=256)
    gemm_xwT<<<dim3(512, 1), 256, 0, stream>>>(ON, Wout, bout, (float*)d_out, 64, 256);
}

// Round 4
// 981.067 us; speedup vs baseline: 1.8764x; 1.8764x over previous
//
#include <hip/hip_runtime.h>
#include <hip/hip_bf16.h>

// Problem: T=512, B=64, N=256, H=64, D=128, P=64.
// Stage 1: x2n = input(32768x128) @ W2n^T(128x256) + b2n          (gemm_xwT)
// Stage 2: 16384 independent LSTM cells scanned over 512 steps    (lstm_scan)
// Stage 3: out = ON(32768x256) @ Wout^T(256x64) + bout            (gemm_xwT)
// Workspace: x2n 32MB + ON 32MB = 64MB of d_ws.
//
// Scan: 2-wave j-split per 16-cell group (2 waves/SIMD for latency hiding).
// Wave w owns gate tiles nt with nt&3 in {2w,2w+1} over full K.  The wave's
// k-slice order is baked into its A-fragment registers at setup (own k-blocks
// first), so per-step B operands are 4 NAMED registers: bown0/1 (kept in reg
// from own nonlinearity output) + bprt0/1 (partner's, one ds_read_b64 pair).
// No runtime-indexed register arrays anywhere (round-3 scratch bug fixed).
// g_t reduction: wave1 parks partials in a 4-deep LDS ring; wave0 consumes
// them 2 steps later (gain_t = g_{t-2} slack); ON[0] written at t==2.

typedef __attribute__((ext_vector_type(4))) float f32x4;
typedef __attribute__((ext_vector_type(4))) short s16x4;
typedef __attribute__((ext_vector_type(8))) short s16x8;
typedef __attribute__((ext_vector_type(2))) unsigned u32x2;

__device__ inline short bf16r(float f) {            // round-to-nearest-even bf16
    unsigned u = __builtin_bit_cast(unsigned, f);
    u += 0x7fffu + ((u >> 16) & 1u);
    return (short)(u >> 16);
}
__device__ inline float bf2f(short s) {
    unsigned u = ((unsigned)(unsigned short)s) << 16;
    return __builtin_bit_cast(float, u);
}
__device__ inline float sigf(float x) {             // 1/(1+e^-x)
    return __builtin_amdgcn_rcpf(1.f + __builtin_amdgcn_exp2f(x * -1.4426950408889634f));
}
__device__ inline float tanh_fast(float x) {        // 1 - 2/(e^{2x}+1)
    return 1.f - 2.f * __builtin_amdgcn_rcpf(1.f + __builtin_amdgcn_exp2f(x * 2.885390081777927f));
}
__device__ inline unsigned pkbf(float a, float b) { // (bf16(a) | bf16(b)<<16), RNE
    unsigned r;
    asm("v_cvt_pk_bf16_f32 %0, %1, %2" : "=v"(r) : "v"(a), "v"(b));
    return r;
}

#if __has_builtin(__builtin_amdgcn_mfma_f32_16x16x16bf16_1k)
#define HAVE_MFMA16 1
__device__ inline f32x4 mfma16(s16x4 a, s16x4 b, f32x4 c) {
    return __builtin_amdgcn_mfma_f32_16x16x16bf16_1k(a, b, c, 0, 0, 0);
}
#else
#define HAVE_MFMA16 0
__device__ inline s16x8 cat8(s16x4 a, s16x4 b) {
    s16x8 r;
    r[0]=a[0]; r[1]=a[1]; r[2]=a[2]; r[3]=a[3];
    r[4]=b[0]; r[5]=b[1]; r[6]=b[2]; r[7]=b[3];
    return r;
}
#endif

// ---------------------------------------------------------------------------
// Generic fp32 GEMM: Out(MxN) = X(MxK) @ Wt(NxK)^T + bias(N).  M%64==0,
// N%64==0, K%32==0.  grid = (M/64, N/64), block = 256.
// ---------------------------------------------------------------------------
__global__ __launch_bounds__(256) void gemm_xwT(
    const float* __restrict__ X, const float* __restrict__ Wt,
    const float* __restrict__ bias, float* __restrict__ Out,
    int N, int K)
{
    __shared__ float Xs[32][68];
    __shared__ float Ws[32][68];
    const int tid = threadIdx.x;
    const int tx = tid & 15, ty = tid >> 4;
    const int m0 = blockIdx.x * 64, n0 = blockIdx.y * 64;
    const int kq = tid & 7, mr = tid >> 3;

    float acc[4][4];
#pragma unroll
    for (int i = 0; i < 4; ++i)
#pragma unroll
        for (int j = 0; j < 4; ++j) acc[i][j] = 0.f;

    for (int kc = 0; kc < K; kc += 32) {
#pragma unroll
        for (int rr = 0; rr < 2; ++rr) {
            const int m = mr + rr * 32;
            f32x4 xv = *(const f32x4*)(X + (size_t)(m0 + m) * K + kc + kq * 4);
            f32x4 wv = *(const f32x4*)(Wt + (size_t)(n0 + m) * K + kc + kq * 4);
#pragma unroll
            for (int j = 0; j < 4; ++j) { Xs[kq*4 + j][m] = xv[j]; Ws[kq*4 + j][m] = wv[j]; }
        }
        __syncthreads();
#pragma unroll
        for (int k = 0; k < 32; ++k) {
            f32x4 a = *(const f32x4*)&Xs[k][ty * 4];
            f32x4 b = *(const f32x4*)&Ws[k][tx * 4];
#pragma unroll
            for (int i = 0; i < 4; ++i)
#pragma unroll
                for (int j = 0; j < 4; ++j)
                    acc[i][j] = __builtin_fmaf(a[i], b[j], acc[i][j]);
        }
        __syncthreads();
    }
    f32x4 bv = *(const f32x4*)(bias + n0 + tx * 4);
#pragma unroll
    for (int i = 0; i < 4; ++i) {
        f32x4 o;
#pragma unroll
        for (int j = 0; j < 4; ++j) o[j] = acc[i][j] + bv[j];
        *(f32x4*)(Out + (size_t)(m0 + ty * 4 + i) * N + n0 + tx * 4) = o;
    }
}

// ---------------------------------------------------------------------------
// Recurrent scan, 2-wave split.  1024 blocks x 128 threads; the block's 16
// cells (cell = cellbase + (lane&15)) are computed jointly by 2 waves.
//
// MFMA layouts (16x16x16 bf16 family), lane l, c15=l&15, g4=l>>4:
//   A: lane holds A[c15][16ks + 4*g4 + e]     (A row = gate nt*16 + c15)
//   B: lane holds B[16ks + 4*g4 + e][c15]
//   D: lane reg e holds D[4*g4 + e][c15]      (gate nt*16 + 4*g4 + e)
//
// Wave w: local tile lt=0..7 -> q = 2w+(lt&1), type = lt>>1, nt = type*4+q.
// Element (ql,e): j = (2w+ql)*16 + 4*g4 + e;  i=acc[ql], f=acc[2+ql],
// g=acc[4+ql], o=acc[6+ql].  New h -> B-fragment ks = 2w+ql.
// afw_l[s] holds the A fragment for k-block (s<2 ? q0+s : partner q0+s-2),
// so the MFMA loop pairs afw_l[0,1] with bown0/1 and afw_l[2,3] with bprt0/1.
// ---------------------------------------------------------------------------
__global__ __launch_bounds__(128, 2) void lstm_scan(
    const float* __restrict__ x2n,   // [512][16384]
    const float* __restrict__ W_hh,  // [256][64]
    const float* __restrict__ w_ih,  // [256]
    const float* __restrict__ b_ih,  // [256]
    const float* __restrict__ b_hh,  // [256]
    const float* __restrict__ wg,    // [64]
    const float* __restrict__ bg,    // [1]
    float* __restrict__ ON)          // [512][16384]
{
    __shared__ short hbuf[2][4][64][4];   // [parity][ks][lane][4] bf16, 4KB
    __shared__ float gbuf[4][16];         // wave1 g-partial ring [t&3][c15]

    const int tid = threadIdx.x;
    const int w = tid >> 6;               // wave id 0/1
    const int lane = tid & 63;
    const int c15 = lane & 15, g4 = lane >> 4;
    const int cellbase = blockIdx.x * 16;
    const int q0 = 2 * w;                 // this wave's first q / ks
    const int ko = 2 - q0;                // partner's first ks

    // A fragments of W_hh for this wave's 8 tiles, k-slice order permuted:
    // s=0,1 -> own k-blocks q0,q0+1 ; s=2,3 -> partner's ko,ko+1.
    s16x4 afw_l[4][8];
    s16x4 afx[8];
#pragma unroll
    for (int lt = 0; lt < 8; ++lt) {
        const int nt = (lt >> 1) * 4 + q0 + (lt & 1);
        const float* wrow = W_hh + (size_t)(nt * 16 + c15) * 64 + g4 * 4;
#pragma unroll
        for (int s = 0; s < 4; ++s) {
            const int ksrc = (s < 2) ? (q0 + s) : (ko + (s - 2));   // addr only
            f32x4 wv = *(const f32x4*)(wrow + ksrc * 16);
            s16x4 bb;
#pragma unroll
            for (int e = 0; e < 4; ++e) bb[e] = bf16r(wv[e]);
            afw_l[s][lt] = bb;
        }
        // Extension slice A row, paired with B-ext (xh, xl, xh, 1 | 1).
        const int g = nt * 16 + c15;
        const float wi = w_ih[g];
        const float bs = b_ih[g] + b_hh[g];
        const short wh = bf16r(wi);
        const short wl = bf16r(wi - bf2f(wh));
        const short bh_ = bf16r(bs);
        const short bl_ = bf16r(bs - bf2f(bh_));
        s16x4 v = (s16x4){0, 0, 0, 0};
        if (g4 == 0) { v[0] = wh; v[1] = wh; v[2] = wl; v[3] = bh_; }
        else if (g4 == 1) { v[0] = bl_; }
        afx[lt] = v;
    }

    // wg slices for this wave's elements: wg_l{0,1}[e] = wg[(q0+ql)*16+4g4+e]
    const f32x4 wg_l0 = *(const f32x4*)(wg + (q0 + 0) * 16 + g4 * 4);
    const f32x4 wg_l1 = *(const f32x4*)(wg + (q0 + 1) * 16 + g4 * 4);
    const float bg0 = bg[0];
    const short one_bf = (short)0x3F80;

    f32x4 cst0 = (f32x4){0.f, 0.f, 0.f, 0.f};
    f32x4 cst1 = (f32x4){0.f, 0.f, 0.f, 0.f};
    s16x4 bown0 = (s16x4){0, 0, 0, 0};
    s16x4 bown1 = (s16x4){0, 0, 0, 0};

    // LDS base pointers (lane-fixed); slot stride 256 shorts, parity 1024.
    short* hlane = &hbuf[0][0][lane][0];
    {   // zero own slots, parity 0
        short* z = hlane + q0 * 256;
        *(s16x4*)z = bown0;
        *(s16x4*)(z + 256) = bown1;
    }
    __syncthreads();

    float xs = x2n[cellbase + c15];       // prefetched x for t=0
    float gp1 = 0.f, gp2 = 0.f, sp0 = 0.f;

    for (int t = 0; t < 512; ++t) {
        const int p = t & 1;

        // partner h fragments (written end of t-1, barrier passed)
        const short* hsrc = hlane + p * 1024 + ko * 256;
        const s16x4 bprt0 = *(const s16x4*)hsrc;
        const s16x4 bprt1 = *(const s16x4*)(hsrc + 256);

        // B extension fragment from x (hi/lo bf16 split)
        const float xs_cur = xs;
        const short xh = bf16r(xs_cur);
        const short xl = bf16r(xs_cur - bf2f(xh));
        s16x4 bx = (s16x4){0, 0, 0, 0};
        if (g4 == 0) { bx[0] = xh; bx[1] = xl; bx[2] = xh; bx[3] = one_bf; }
        else if (g4 == 1) { bx[0] = one_bf; }
        xs = x2n[(size_t)((t + 1) & 511) * 16384 + cellbase + c15]; // branchless

        // gates for this wave's 8 tiles: ext + own k-blocks + partner k-blocks
        f32x4 acc[8];
        const f32x4 zero4 = (f32x4){0.f, 0.f, 0.f, 0.f};
#if HAVE_MFMA16
#pragma unroll
        for (int lt = 0; lt < 8; ++lt) acc[lt] = mfma16(afx[lt], bx, zero4);
#pragma unroll
        for (int lt = 0; lt < 8; ++lt) acc[lt] = mfma16(afw_l[0][lt], bown0, acc[lt]);
#pragma unroll
        for (int lt = 0; lt < 8; ++lt) acc[lt] = mfma16(afw_l[1][lt], bown1, acc[lt]);
#pragma unroll
        for (int lt = 0; lt < 8; ++lt) acc[lt] = mfma16(afw_l[2][lt], bprt0, acc[lt]);
#pragma unroll
        for (int lt = 0; lt < 8; ++lt) acc[lt] = mfma16(afw_l[3][lt], bprt1, acc[lt]);
#else
        {
            const s16x4 z4 = (s16x4){0, 0, 0, 0};
            s16x8 bx8 = cat8(bx, z4);
            s16x8 b01 = cat8(bown0, bown1);
            s16x8 b23 = cat8(bprt0, bprt1);
#pragma unroll
            for (int lt = 0; lt < 8; ++lt) {
                acc[lt] = __builtin_amdgcn_mfma_f32_16x16x32_bf16(cat8(afx[lt], z4), bx8, zero4, 0, 0, 0);
                acc[lt] = __builtin_amdgcn_mfma_f32_16x16x32_bf16(cat8(afw_l[0][lt], afw_l[1][lt]), b01, acc[lt], 0, 0, 0);
                acc[lt] = __builtin_amdgcn_mfma_f32_16x16x32_bf16(cat8(afw_l[2][lt], afw_l[3][lt]), b23, acc[lt], 0, 0, 0);
            }
        }
#endif

        // nonlinearities for this wave's 8 elements (ql=0,1 named)
        f32x4 hvf0, hvf1;
        {
            f32x4 cn, hn;
#pragma unroll
            for (int e = 0; e < 4; ++e) {
                const float iv = acc[0][e], fv = acc[2][e];
                const float gv = acc[4][e], ov = acc[6][e];
                const float c2 = sigf(fv) * cst0[e] + sigf(iv) * tanh_fast(gv);
                cn[e] = c2;
                hn[e] = sigf(ov) * tanh_fast(c2);
            }
            cst0 = cn;
            hvf0 = hn;
        }
        {
            f32x4 cn, hn;
#pragma unroll
            for (int e = 0; e < 4; ++e) {
                const float iv = acc[1][e], fv = acc[3][e];
                const float gv = acc[5][e], ov = acc[7][e];
                const float c2 = sigf(fv) * cst1[e] + sigf(iv) * tanh_fast(gv);
                cn[e] = c2;
                hn[e] = sigf(ov) * tanh_fast(c2);
            }
            cst1 = cn;
            hvf1 = hn;
        }

        // pack h -> bf16 B-fragments (v_cvt_pk_bf16_f32, RNE) + publish
        bown0 = __builtin_bit_cast(s16x4,
                    (u32x2){pkbf(hvf0[0], hvf0[1]), pkbf(hvf0[2], hvf0[3])});
        bown1 = __builtin_bit_cast(s16x4,
                    (u32x2){pkbf(hvf1[0], hvf1[1]), pkbf(hvf1[2], hvf1[3])});
        {
            short* hdst = hlane + (p ^ 1) * 1024 + q0 * 256;
            *(s16x4*)hdst = bown0;
            *(s16x4*)(hdst + 256) = bown1;
        }

        // g_t partial over this wave's j-half, reduced across g4 groups
        float gpart = 0.f;
#pragma unroll
        for (int e = 0; e < 4; ++e) {
            gpart = __builtin_fmaf(hvf0[e], wg_l0[e], gpart);
            gpart = __builtin_fmaf(hvf1[e], wg_l1[e], gpart);
        }
        gpart += __shfl_xor(gpart, 16, 64);
        gpart += __shfl_xor(gpart, 32, 64);

        if (w == 1) {
            if (g4 == 0) gbuf[t & 3][c15] = gpart;   // park partial for wave0
        } else {
            // softplus(x-1)
            const float x1 = xs_cur - 1.f;
            const float sp = fmaxf(x1, 0.f) +
                0.6931471805599453f * __builtin_amdgcn_logf(
                    1.f + __builtin_amdgcn_exp2f(-1.4426950408889634f * fabsf(x1)));
            if (t == 0) {
                sp0 = sp;                            // ON[0] deferred to t==2
            } else if (t == 1) {
                if (g4 == 0) ON[(size_t)16384 + cellbase + c15] = sp;  // gain=1
            } else {
                const float gain = gp2 + gbuf[(t - 2) & 3][c15] + bg0; // g_{t-2}
                if (g4 == 0) {
                    ON[(size_t)t * 16384 + cellbase + c15] = gain * sp;
                    if (t == 2) ON[cellbase + c15] = gain * sp0;       // g_0 too
                }
            }
            gp2 = gp1;
            gp1 = gpart;
        }

        __syncthreads();   // h(t+1 parity) + gbuf visible for next step
    }
}

extern "C" void kernel_launch(void* const* d_in, const int* in_sizes, int n_in,
                              void* d_out, int out_size, void* d_ws, size_t ws_size,
                              hipStream_t stream)
{
    const float* input = (const float*)d_in[0];   // [512][64][128]
    const float* W2n   = (const float*)d_in[1];   // [256][128]
    const float* b2n   = (const float*)d_in[2];   // [256]
    const float* W_ih  = (const float*)d_in[3];   // [256] (4H x 1)
    const float* W_hh  = (const float*)d_in[4];   // [256][64]
    const float* b_ih  = (const float*)d_in[5];   // [256]
    const float* b_hh  = (const float*)d_in[6];   // [256]
    const float* Wg    = (const float*)d_in[7];   // [64]  (1 x H)
    const float* bg    = (const float*)d_in[8];   // [1]
    const float* Wout  = (const float*)d_in[9];   // [64][256]
    const float* bout  = (const float*)d_in[10];  // [64]

    float* x2n = (float*)d_ws;                          // 512*16384 f32 = 32MB
    float* ON  = x2n + (size_t)512 * 16384;             // another 32MB

    // Stage 1: x2n = input @ W2n^T + b2n   (M=32768, N=256, K=128)
    gemm_xwT<<<dim3(512, 4), 256, 0, stream>>>(input, W2n, b2n, x2n, 256, 128);

    // Stage 2: recurrent scan -> ON
    lstm_scan<<<1024, 128, 0, stream>>>(x2n, W_hh, W_ih, b_ih, b_hh, Wg, bg, ON);

    // Stage 3: out = ON @ Wout^T + bout    (M=32768, N=64, K=256)
    gemm_xwT<<<dim3(512, 1), 256, 0, stream>>>(ON, Wout, bout, (float*)d_out, 64, 256);
}

// Round 6
// 949.967 us; speedup vs baseline: 1.9378x; 1.0327x over previous
//
#include <hip/hip_runtime.h>
#include <hip/hip_bf16.h>

// Problem: T=512, B=64, N=256, H=64, D=128, P=64.
// Stage 1: x2n = input(32768x128) @ W2n^T(128x256) + b2n          (gemm_xwT)
// Stage 2: 16384 independent LSTM cells scanned over 512 steps    (lstm_scan)
// Stage 3: out = ON(32768x256) @ Wout^T(256x64) + bout            (gemm_xwT)
// Workspace: x2n 32MB + ON 32MB = 64MB of d_ws.
//
// Scan (round-6 = round-5 with the host-pass compile fix): single wave per
// 16-cell group (rounds 3/4 proved VALU/trans pipes are shared across waves,
// so occupancy is a dead lever; cutting issued cycles is the live one).
//   - A-fragments pre-scaled by -log2e (i,f,o) / +2*log2e (g): gates emerge
//     from MFMA as ready exp2 arguments (no per-element scaling muls).
//   - Merged nonlinearities: sig(i)*tanh(g) = (v-1)*rcp((1+u)(1+v)) [1 rcp
//     for 2 funcs], same for sig(o)*tanh(c'); sig(f) rcps paired two-at-a-
//     time via rcp(a*b).  7.5 trans/element vs 10.
//   - h -> bf16 via v_cvt_pk_bf16_f32 (8 instr vs ~64).
//   - g-reduction shuffles deferred 2 steps (gain_t = g_{t-2} slack) so
//     shuffle latency is off the critical path; branchless x prefetch.

typedef __attribute__((ext_vector_type(4))) float f32x4;
typedef __attribute__((ext_vector_type(4))) short s16x4;
typedef __attribute__((ext_vector_type(8))) short s16x8;
typedef __attribute__((ext_vector_type(2))) unsigned u32x2;

__device__ inline short bf16r(float f) {            // round-to-nearest-even bf16
    unsigned u = __builtin_bit_cast(unsigned, f);
    u += 0x7fffu + ((u >> 16) & 1u);
    return (short)(u >> 16);
}
__device__ inline float bf2f(short s) {
    unsigned u = ((unsigned)(unsigned short)s) << 16;
    return __builtin_bit_cast(float, u);
}
__device__ inline unsigned pkbf(float a, float b) { // (bf16(a) | bf16(b)<<16), RNE
    unsigned r;
    asm("v_cvt_pk_bf16_f32 %0, %1, %2" : "=v"(r) : "v"(a), "v"(b));
    return r;
}

#if __has_builtin(__builtin_amdgcn_mfma_f32_16x16x16bf16_1k)
#define HAVE_MFMA16 1
__device__ inline f32x4 mfma16(s16x4 a, s16x4 b, f32x4 c) {
    return __builtin_amdgcn_mfma_f32_16x16x16bf16_1k(a, b, c, 0, 0, 0);
}
#else
#define HAVE_MFMA16 0
#endif
__device__ inline s16x8 cat8(s16x4 a, s16x4 b) {
    s16x8 r;
    r[0]=a[0]; r[1]=a[1]; r[2]=a[2]; r[3]=a[3];
    r[4]=b[0]; r[5]=b[1]; r[6]=b[2]; r[7]=b[3];
    return r;
}

// ---------------------------------------------------------------------------
// Generic fp32 GEMM: Out(MxN) = X(MxK) @ Wt(NxK)^T + bias(N).  M%64==0,
// N%64==0, K%32==0.  grid = (M/64, N/64), block = 256.
// ---------------------------------------------------------------------------
__global__ __launch_bounds__(256) void gemm_xwT(
    const float* __restrict__ X, const float* __restrict__ Wt,
    const float* __restrict__ bias, float* __restrict__ Out,
    int N, int K)
{
    __shared__ float Xs[32][68];
    __shared__ float Ws[32][68];
    const int tid = threadIdx.x;
    const int tx = tid & 15, ty = tid >> 4;
    const int m0 = blockIdx.x * 64, n0 = blockIdx.y * 64;
    const int kq = tid & 7, mr = tid >> 3;

    float acc[4][4];
#pragma unroll
    for (int i = 0; i < 4; ++i)
#pragma unroll
        for (int j = 0; j < 4; ++j) acc[i][j] = 0.f;

    for (int kc = 0; kc < K; kc += 32) {
#pragma unroll
        for (int rr = 0; rr < 2; ++rr) {
            const int m = mr + rr * 32;
            f32x4 xv = *(const f32x4*)(X + (size_t)(m0 + m) * K + kc + kq * 4);
            f32x4 wv = *(const f32x4*)(Wt + (size_t)(n0 + m) * K + kc + kq * 4);
#pragma unroll
            for (int j = 0; j < 4; ++j) { Xs[kq*4 + j][m] = xv[j]; Ws[kq*4 + j][m] = wv[j]; }
        }
        __syncthreads();
#pragma unroll
        for (int k = 0; k < 32; ++k) {
            f32x4 a = *(const f32x4*)&Xs[k][ty * 4];
            f32x4 b = *(const f32x4*)&Ws[k][tx * 4];
#pragma unroll
            for (int i = 0; i < 4; ++i)
#pragma unroll
                for (int j = 0; j < 4; ++j)
                    acc[i][j] = __builtin_fmaf(a[i], b[j], acc[i][j]);
        }
        __syncthreads();
    }
    f32x4 bv = *(const f32x4*)(bias + n0 + tx * 4);
#pragma unroll
    for (int i = 0; i < 4; ++i) {
        f32x4 o;
#pragma unroll
        for (int j = 0; j < 4; ++j) o[j] = acc[i][j] + bv[j];
        *(f32x4*)(Out + (size_t)(m0 + ty * 4 + i) * N + n0 + tx * 4) = o;
    }
}

// ---------------------------------------------------------------------------
// Recurrent scan, register-only h.  1024 blocks x 64 threads; each wave owns
// 16 cells (cell = cellbase + (lane&15)) for all 512 steps.
//
// MFMA layouts (16x16x16 bf16 family), lane l, c15=l&15, g4=l>>4:
//   A: lane holds A[c15][16ks + 4*g4 + e]
//   B: lane holds B[16ks + 4*g4 + e][c15]
//   D: lane reg e holds D[4*g4 + e][c15]
//
// acc[nt] (nt=0..15): lane (g4,c15) elem e = PRE-SCALED gate nt*16+4g4+e of
// cell c15; type=nt>>2 in {i,f,g,o}; scale -log2e for i/f/o, +2log2e for g.
// ---------------------------------------------------------------------------
__global__ __launch_bounds__(64, 1) void lstm_scan(
    const float* __restrict__ x2n,   // [512][16384]
    const float* __restrict__ W_hh,  // [256][64]
    const float* __restrict__ w_ih,  // [256]
    const float* __restrict__ b_ih,  // [256]
    const float* __restrict__ b_hh,  // [256]
    const float* __restrict__ wg,    // [64]
    const float* __restrict__ bg,    // [1]
    float* __restrict__ ON)          // [512][16384]
{
    const int lane = threadIdx.x & 63;
    const int c15 = lane & 15, g4 = lane >> 4;
    const int cellbase = blockIdx.x * 16;

    const float L2E = 1.4426950408889634f;   // log2(e)

    // A fragments of W_hh (row = gate nt*16+c15, k = 16ks+4g4+e), PRE-SCALED
    s16x4 afw[4][16];
    s16x4 afx[16];
#pragma unroll
    for (int nt = 0; nt < 16; ++nt) {
        const int type = nt >> 2;
        const float sc = (type == 2) ? (2.f * L2E) : (-L2E);
        const float* wrow = W_hh + (size_t)(nt * 16 + c15) * 64;
#pragma unroll
        for (int ks = 0; ks < 4; ++ks) {
            f32x4 w = *(const f32x4*)(wrow + ks * 16 + g4 * 4);
            s16x4 bb;
#pragma unroll
            for (int e = 0; e < 4; ++e) bb[e] = bf16r(w[e] * sc);
            afw[ks][nt] = bb;
        }
        // Extension slice A row, paired with B-ext (xh, xl, xh, 1 | 1).
        const int g = nt * 16 + c15;
        const float wi = w_ih[g] * sc;
        const float bs = (b_ih[g] + b_hh[g]) * sc;
        const short wh = bf16r(wi);
        const short wl = bf16r(wi - bf2f(wh));
        const short bh_ = bf16r(bs);
        const short bl_ = bf16r(bs - bf2f(bh_));
        s16x4 v = (s16x4){0, 0, 0, 0};
        if (g4 == 0) { v[0] = wh; v[1] = wh; v[2] = wl; v[3] = bh_; }
        else if (g4 == 1) { v[0] = bl_; }
        afx[nt] = v;
    }

    // wg, laid out to match hvf: wg_l[q][e] = wg[q*16 + 4*g4 + e]
    f32x4 wg_l[4];
#pragma unroll
    for (int q = 0; q < 4; ++q) wg_l[q] = *(const f32x4*)(wg + q * 16 + g4 * 4);
    const float bg0 = bg[0];
    const short one_bf = (short)0x3F80;

    f32x4 cst[4];
    s16x4 bh[4];                      // h_{t-1} as B-fragments (bf16)
#pragma unroll
    for (int q = 0; q < 4; ++q) {
        cst[q] = (f32x4){0.f, 0.f, 0.f, 0.f};
        bh[q] = (s16x4){0, 0, 0, 0};
    }
    float gpraw1 = 0.f, gpraw2 = 0.f, sp0 = 0.f;

    float xs = x2n[cellbase + c15];   // x for (t=0, cell c15), prefetched

    for (int t = 0; t < 512; ++t) {
        // ---- deferred g-reduction: finish the t-2 partial (latency hidden
        // behind this whole step's MFMA + nonlinearity work)
        float g2r = gpraw2;
        g2r += __shfl_xor(g2r, 16, 64);
        g2r += __shfl_xor(g2r, 32, 64);

        // B extension fragment from x (hi/lo bf16 split)
        const float xs_cur = xs;
        const short xh = bf16r(xs_cur);
        const short xl = bf16r(xs_cur - bf2f(xh));
        s16x4 bx = (s16x4){0, 0, 0, 0};
        if (g4 == 0) { bx[0] = xh; bx[1] = xl; bx[2] = xh; bx[3] = one_bf; }
        else if (g4 == 1) { bx[0] = one_bf; }
        xs = x2n[(size_t)((t + 1) & 511) * 16384 + cellbase + c15]; // branchless

        // gates^T (pre-scaled): ext slice init + 4 K-slices of W_hh @ h^T
        f32x4 acc[16];
        const f32x4 zero4 = (f32x4){0.f, 0.f, 0.f, 0.f};
#if HAVE_MFMA16
#pragma unroll
        for (int nt = 0; nt < 16; ++nt) acc[nt] = mfma16(afx[nt], bx, zero4);
#pragma unroll
        for (int ks = 0; ks < 4; ++ks)
#pragma unroll
            for (int nt = 0; nt < 16; ++nt)
                acc[nt] = mfma16(afw[ks][nt], bh[ks], acc[nt]);
#else
        // two stacked 16x16x16 halves per 16x16x32 op (elems 0-3 = k-block,
        // 4-7 = next k-block)
        {
            const s16x4 z4 = (s16x4){0, 0, 0, 0};
            s16x8 bx8 = cat8(bx, z4);
            s16x8 b01 = cat8(bh[0], bh[1]);
            s16x8 b23 = cat8(bh[2], bh[3]);
#pragma unroll
            for (int nt = 0; nt < 16; ++nt) {
                acc[nt] = __builtin_amdgcn_mfma_f32_16x16x32_bf16(cat8(afx[nt], z4), bx8, zero4, 0, 0, 0);
                acc[nt] = __builtin_amdgcn_mfma_f32_16x16x32_bf16(cat8(afw[0][nt], afw[1][nt]), b01, acc[nt], 0, 0, 0);
                acc[nt] = __builtin_amdgcn_mfma_f32_16x16x32_bf16(cat8(afw[2][nt], afw[3][nt]), b23, acc[nt], 0, 0, 0);
            }
        }
#endif

        // ---- merged nonlinearities ----
        // per element: is_=acc[q] (-1.4427*i), fs_=acc[q+4], gs_=acc[q+8]
        // (2.885*g), os_=acc[q+12].
        //   u=exp2(is_)=e^-i etc.; sig(i)*tanh(g) = (v-1)*rcp((1+u)(1+v));
        //   sig(f) rcps paired: rf = rcp(dfa*dfb);
        //   h = sig(o)*tanh(c') = (vc-1)*rcp((1+uo)(1+vc)).
        f32x4 hvf[4];
#pragma unroll
        for (int qp = 0; qp < 2; ++qp) {
            const int qa = 2 * qp, qb = qa + 1;
            f32x4 cna, cnb, hna, hnb;
#pragma unroll
            for (int e = 0; e < 4; ++e) {
                const float ufa = __builtin_amdgcn_exp2f(fminf(acc[qa + 4][e], 43.f));
                const float ufb = __builtin_amdgcn_exp2f(fminf(acc[qb + 4][e], 43.f));
                const float dfa = 1.f + ufa, dfb = 1.f + ufb;
                const float rf = __builtin_amdgcn_rcpf(dfa * dfb);
                const float sfa = rf * dfb, sfb = rf * dfa;

                const float uia = __builtin_amdgcn_exp2f(acc[qa][e]);
                const float uib = __builtin_amdgcn_exp2f(acc[qb][e]);
                const float vga = __builtin_amdgcn_exp2f(fminf(acc[qa + 8][e], 43.f));
                const float vgb = __builtin_amdgcn_exp2f(fminf(acc[qb + 8][e], 43.f));
                const float pa = (vga - 1.f) *
                    __builtin_amdgcn_rcpf((1.f + uia) * (1.f + vga));
                const float pb = (vgb - 1.f) *
                    __builtin_amdgcn_rcpf((1.f + uib) * (1.f + vgb));

                const float ca = __builtin_fmaf(sfa, cst[qa][e], pa);
                const float cb = __builtin_fmaf(sfb, cst[qb][e], pb);
                cna[e] = ca; cnb[e] = cb;

                const float uoa = __builtin_amdgcn_exp2f(acc[qa + 12][e]);
                const float uob = __builtin_amdgcn_exp2f(acc[qb + 12][e]);
                const float vca = __builtin_amdgcn_exp2f(fminf(2.8853900817779268f * ca, 43.f));
                const float vcb = __builtin_amdgcn_exp2f(fminf(2.8853900817779268f * cb, 43.f));
                hna[e] = (vca - 1.f) * __builtin_amdgcn_rcpf((1.f + uoa) * (1.f + vca));
                hnb[e] = (vcb - 1.f) * __builtin_amdgcn_rcpf((1.f + uob) * (1.f + vcb));
            }
            cst[qa] = cna; cst[qb] = cnb;
            hvf[qa] = hna; hvf[qb] = hnb;
        }

        // next-step B fragments via packed cvt (RNE)
#pragma unroll
        for (int q = 0; q < 4; ++q)
            bh[q] = __builtin_bit_cast(s16x4,
                        (u32x2){pkbf(hvf[q][0], hvf[q][1]), pkbf(hvf[q][2], hvf[q][3])});

        // g_t raw partial (shuffle-reduce deferred 2 steps)
        float gpart = 0.f;
#pragma unroll
        for (int q = 0; q < 4; ++q)
#pragma unroll
            for (int e = 0; e < 4; ++e)
                gpart = __builtin_fmaf(hvf[q][e], wg_l[q][e], gpart);

        // out[t,cell] = gain * softplus(x-1); gain = g_t, 1, g_{t-2}
        const float x1 = xs_cur - 1.f;
        const float sp = fmaxf(x1, 0.f) +
            0.6931471805599453f * __builtin_amdgcn_logf(
                1.f + __builtin_amdgcn_exp2f(-1.4426950408889634f * fabsf(x1)));
        if (t >= 2) {
            const float gain = g2r + bg0;            // = g_{t-2}
            if (g4 == 0) {
                ON[(size_t)t * 16384 + cellbase + c15] = gain * sp;
                if (t == 2) ON[cellbase + c15] = gain * sp0;   // gain_0 = g_0
            }
        } else if (t == 1) {
            if (g4 == 0) ON[(size_t)16384 + cellbase + c15] = sp;  // gain=1
        } else {
            sp0 = sp;                                // ON[0] deferred to t==2
        }
        gpraw2 = gpraw1;
        gpraw1 = gpart;
    }
}

extern "C" void kernel_launch(void* const* d_in, const int* in_sizes, int n_in,
                              void* d_out, int out_size, void* d_ws, size_t ws_size,
                              hipStream_t stream)
{
    const float* input = (const float*)d_in[0];   // [512][64][128]
    const float* W2n   = (const float*)d_in[1];   // [256][128]
    const float* b2n   = (const float*)d_in[2];   // [256]
    const float* W_ih  = (const float*)d_in[3];   // [256] (4H x 1)
    const float* W_hh  = (const float*)d_in[4];   // [256][64]
    const float* b_ih  = (const float*)d_in[5];   // [256]
    const float* b_hh  = (const float*)d_in[6];   // [256]
    const float* Wg    = (const float*)d_in[7];   // [64]  (1 x H)
    const float* bg    = (const float*)d_in[8];   // [1]
    const float* Wout  = (const float*)d_in[9];   // [64][256]
    const float* bout  = (const float*)d_in[10];  // [64]

    float* x2n = (float*)d_ws;                          // 512*16384 f32 = 32MB
    float* ON  = x2n + (size_t)512 * 16384;             // another 32MB

    // Stage 1: x2n = input @ W2n^T + b2n   (M=32768, N=256, K=128)
    gemm_xwT<<<dim3(512, 4), 256, 0, stream>>>(input, W2n, b2n, x2n, 256, 128);

    // Stage 2: recurrent scan -> ON
    lstm_scan<<<1024, 64, 0, stream>>>(x2n, W_hh, W_ih, b_ih, b_hh, Wg, bg, ON);

    // Stage 3: out = ON @ Wout^T + bout    (M=32768, N=64, K=256)
    gemm_xwT<<<dim3(512, 1), 256, 0, stream>>>(ON, Wout, bout, (float*)d_out, 64, 256);
}

// Round 7
// 813.220 us; speedup vs baseline: 2.2637x; 1.1682x over previous
//
#include <hip/hip_runtime.h>
#include <hip/hip_bf16.h>

// Problem: T=512, B=64, N=256, H=64, D=128, P=64.
// Stage 1: x2n = input(32768x128) @ W2n^T(128x256) + b2n          (gemm_xwT)
// Stage 2: 16384 independent LSTM cells scanned over 512 steps    (lstm_scan)
// Stage 3: out = ON(32768x256) @ Wout^T(256x64) + bout            (gemm_xwT)
// Workspace: x2n 32MB + ON 32MB = 64MB of d_ws.
//
// Scan (round-7): single wave per 16-cell group.  Changes vs round-6:
//   - Native CDNA4 K=32 MFMA (mfma_f32_16x16x32_bf16): 48 issues/step vs 80,
//     half the matrix-pipe occupancy (legacy K=16 shape runs at half rate).
//     A/B layout = two stacked K=16 halves (elems 0-3 = k-block, 4-7 = +16),
//     confirmed by the ds_read_b64_tr_b16 lane mapping (learn_hip m156/m162).
//   - Weight fragments PINNED resident via asm "+v" (round-6 reported
//     VGPR_Count=160 vs ~330 live: compiler was re-loading weights from
//     global every step; pinning breaks rematerialization).
//   - f/g exp2 clamps dropped (|pre-act| provably < 30 -> no overflow);
//     c' clamp kept (cell state can grow over 512 steps).
//   - g-reduction shuffles split across iterations (s1 at end of step t,
//     s2 at start of t+1, consumed at t+2 = exactly the g_{t-2} gain slack).

typedef __attribute__((ext_vector_type(4))) float f32x4;
typedef __attribute__((ext_vector_type(4))) short s16x4;
typedef __attribute__((ext_vector_type(8))) short s16x8;
typedef __attribute__((ext_vector_type(4))) unsigned u32x4;

__device__ inline short bf16r(float f) {            // round-to-nearest-even bf16
    unsigned u = __builtin_bit_cast(unsigned, f);
    u += 0x7fffu + ((u >> 16) & 1u);
    return (short)(u >> 16);
}
__device__ inline float bf2f(short s) {
    unsigned u = ((unsigned)(unsigned short)s) << 16;
    return __builtin_bit_cast(float, u);
}
__device__ inline unsigned pkbf(float a, float b) { // (bf16(a) | bf16(b)<<16), RNE
    unsigned r;
    asm("v_cvt_pk_bf16_f32 %0, %1, %2" : "=v"(r) : "v"(a), "v"(b));
    return r;
}
__device__ inline f32x4 mfma32(s16x8 a, s16x8 b, f32x4 c) {
    return __builtin_amdgcn_mfma_f32_16x16x32_bf16(a, b, c, 0, 0, 0);
}

// ---------------------------------------------------------------------------
// Generic fp32 GEMM: Out(MxN) = X(MxK) @ Wt(NxK)^T + bias(N).  M%64==0,
// N%64==0, K%32==0.  grid = (M/64, N/64), block = 256.
// ---------------------------------------------------------------------------
__global__ __launch_bounds__(256) void gemm_xwT(
    const float* __restrict__ X, const float* __restrict__ Wt,
    const float* __restrict__ bias, float* __restrict__ Out,
    int N, int K)
{
    __shared__ float Xs[32][68];
    __shared__ float Ws[32][68];
    const int tid = threadIdx.x;
    const int tx = tid & 15, ty = tid >> 4;
    const int m0 = blockIdx.x * 64, n0 = blockIdx.y * 64;
    const int kq = tid & 7, mr = tid >> 3;

    float acc[4][4];
#pragma unroll
    for (int i = 0; i < 4; ++i)
#pragma unroll
        for (int j = 0; j < 4; ++j) acc[i][j] = 0.f;

    for (int kc = 0; kc < K; kc += 32) {
#pragma unroll
        for (int rr = 0; rr < 2; ++rr) {
            const int m = mr + rr * 32;
            f32x4 xv = *(const f32x4*)(X + (size_t)(m0 + m) * K + kc + kq * 4);
            f32x4 wv = *(const f32x4*)(Wt + (size_t)(n0 + m) * K + kc + kq * 4);
#pragma unroll
            for (int j = 0; j < 4; ++j) { Xs[kq*4 + j][m] = xv[j]; Ws[kq*4 + j][m] = wv[j]; }
        }
        __syncthreads();
#pragma unroll
        for (int k = 0; k < 32; ++k) {
            f32x4 a = *(const f32x4*)&Xs[k][ty * 4];
            f32x4 b = *(const f32x4*)&Ws[k][tx * 4];
#pragma unroll
            for (int i = 0; i < 4; ++i)
#pragma unroll
                for (int j = 0; j < 4; ++j)
                    acc[i][j] = __builtin_fmaf(a[i], b[j], acc[i][j]);
        }
        __syncthreads();
    }
    f32x4 bv = *(const f32x4*)(bias + n0 + tx * 4);
#pragma unroll
    for (int i = 0; i < 4; ++i) {
        f32x4 o;
#pragma unroll
        for (int j = 0; j < 4; ++j) o[j] = acc[i][j] + bv[j];
        *(f32x4*)(Out + (size_t)(m0 + ty * 4 + i) * N + n0 + tx * 4) = o;
    }
}

// ---------------------------------------------------------------------------
// Recurrent scan, register-only h.  1024 blocks x 64 threads; each wave owns
// 16 cells (cell = cellbase + (lane&15)) for all 512 steps.
//
// MFMA 16x16x32 bf16 layouts, lane l, c15=l&15, g4=l>>4:
//   A: lane elems 0-3 hold A[c15][kbase + 4*g4 + e], elems 4-7: +16
//   B: lane elems 0-3 hold B[kbase + 4*g4 + e][c15], elems 4-7: +16
//   D: lane reg e holds D[4*g4 + e][c15]
//
// acc[nt] (nt=0..15): lane (g4,c15) elem e = PRE-SCALED gate nt*16+4g4+e of
// cell c15; type=nt>>2 in {i,f,g,o}; scale -log2e for i/f/o, +2log2e for g.
// ---------------------------------------------------------------------------
__global__ __launch_bounds__(64, 1) void lstm_scan(
    const float* __restrict__ x2n,   // [512][16384]
    const float* __restrict__ W_hh,  // [256][64]
    const float* __restrict__ w_ih,  // [256]
    const float* __restrict__ b_ih,  // [256]
    const float* __restrict__ b_hh,  // [256]
    const float* __restrict__ wg,    // [64]
    const float* __restrict__ bg,    // [1]
    float* __restrict__ ON)          // [512][16384]
{
    const int lane = threadIdx.x & 63;
    const int c15 = lane & 15, g4 = lane >> 4;
    const int cellbase = blockIdx.x * 16;

    const float L2E = 1.4426950408889634f;   // log2(e)

    // W_hh A-fragments (K=32 pairs) + ext-slice fragments, PRE-SCALED.
    s16x8 afw8[2][16];
    s16x8 afx8[16];
#pragma unroll
    for (int nt = 0; nt < 16; ++nt) {
        const int type = nt >> 2;
        const float sc = (type == 2) ? (2.f * L2E) : (-L2E);
        const float* wrow = W_hh + (size_t)(nt * 16 + c15) * 64;
#pragma unroll
        for (int kp = 0; kp < 2; ++kp) {
            s16x8 v;
#pragma unroll
            for (int half = 0; half < 2; ++half) {
                f32x4 w = *(const f32x4*)(wrow + (kp * 2 + half) * 16 + g4 * 4);
#pragma unroll
                for (int e = 0; e < 4; ++e) v[half * 4 + e] = bf16r(w[e] * sc);
            }
            afw8[kp][nt] = v;
        }
        // Ext slice A row, paired with B-ext (xh, xl, xh, 1 | 1); hi half 0.
        const int g = nt * 16 + c15;
        const float wi = w_ih[g] * sc;
        const float bs = (b_ih[g] + b_hh[g]) * sc;
        const short wh = bf16r(wi);
        const short wl = bf16r(wi - bf2f(wh));
        const short bh_ = bf16r(bs);
        const short bl_ = bf16r(bs - bf2f(bh_));
        s16x8 v = (s16x8){0, 0, 0, 0, 0, 0, 0, 0};
        if (g4 == 0) { v[0] = wh; v[1] = wh; v[2] = wl; v[3] = bh_; }
        else if (g4 == 1) { v[0] = bl_; }
        afx8[nt] = v;
    }
    // Pin every weight fragment: breaks rematerialization-from-memory so the
    // compiler keeps them resident (round-6: VGPR_Count=160 vs ~330 live ->
    // it was re-loading weights from global every timestep).
#pragma unroll
    for (int nt = 0; nt < 16; ++nt) {
        asm volatile("" : "+v"(afw8[0][nt]));
        asm volatile("" : "+v"(afw8[1][nt]));
        asm volatile("" : "+v"(afx8[nt]));
    }

    // wg, laid out to match hvf: wg_l[q][e] = wg[q*16 + 4*g4 + e]
    f32x4 wg_l[4];
#pragma unroll
    for (int q = 0; q < 4; ++q) wg_l[q] = *(const f32x4*)(wg + q * 16 + g4 * 4);
    const float bg0 = bg[0];
    const short one_bf = (short)0x3F80;

    f32x4 cst[4];
#pragma unroll
    for (int q = 0; q < 4; ++q) cst[q] = (f32x4){0.f, 0.f, 0.f, 0.f};
    s16x8 bh01 = (s16x8){0, 0, 0, 0, 0, 0, 0, 0};   // h k=0..31  B-fragment
    s16x8 bh23 = (s16x8){0, 0, 0, 0, 0, 0, 0, 0};   // h k=32..63 B-fragment

    float g_s1 = 0.f;      // xor16-reduced g-partial of step t-1
    float g2save = 0.f;    // fully-reduced g of step t-2
    float sp0 = 0.f;

    float xs = x2n[cellbase + c15];   // x for (t=0, cell c15), prefetched

    for (int t = 0; t < 512; ++t) {
        // finish step t-1's g-reduction (independent of everything below)
        const float s2new = g_s1 + __shfl_xor(g_s1, 32, 64);

        // B extension fragment from x (hi/lo bf16 split), hi half zero
        const float xs_cur = xs;
        const short xh = bf16r(xs_cur);
        const short xl = bf16r(xs_cur - bf2f(xh));
        s16x8 bx8 = (s16x8){0, 0, 0, 0, 0, 0, 0, 0};
        if (g4 == 0) { bx8[0] = xh; bx8[1] = xl; bx8[2] = xh; bx8[3] = one_bf; }
        else if (g4 == 1) { bx8[0] = one_bf; }
        xs = x2n[(size_t)((t + 1) & 511) * 16384 + cellbase + c15]; // branchless

        // gates^T (pre-scaled): ext K-slice + two K=32 slices of W_hh @ h^T
        f32x4 acc[16];
        const f32x4 zero4 = (f32x4){0.f, 0.f, 0.f, 0.f};
#pragma unroll
        for (int nt = 0; nt < 16; ++nt) acc[nt] = mfma32(afx8[nt], bx8, zero4);
#pragma unroll
        for (int nt = 0; nt < 16; ++nt) acc[nt] = mfma32(afw8[0][nt], bh01, acc[nt]);
#pragma unroll
        for (int nt = 0; nt < 16; ++nt) acc[nt] = mfma32(afw8[1][nt], bh23, acc[nt]);

        // ---- merged nonlinearities (rcp-paired across qa/qb) ----
        f32x4 hvf[4];
#pragma unroll
        for (int qp = 0; qp < 2; ++qp) {
            const int qa = 2 * qp, qb = qa + 1;
            f32x4 cna, cnb, hna, hnb;
#pragma unroll
            for (int e = 0; e < 4; ++e) {
                const float ufa = __builtin_amdgcn_exp2f(acc[qa + 4][e]);
                const float ufb = __builtin_amdgcn_exp2f(acc[qb + 4][e]);
                const float dfa = 1.f + ufa, dfb = 1.f + ufb;
                const float rf = __builtin_amdgcn_rcpf(dfa * dfb);
                const float sfa = rf * dfb, sfb = rf * dfa;

                const float uia = __builtin_amdgcn_exp2f(acc[qa][e]);
                const float uib = __builtin_amdgcn_exp2f(acc[qb][e]);
                const float vga = __builtin_amdgcn_exp2f(acc[qa + 8][e]);
                const float vgb = __builtin_amdgcn_exp2f(acc[qb + 8][e]);
                const float pa = (vga - 1.f) *
                    __builtin_amdgcn_rcpf((1.f + uia) * (1.f + vga));
                const float pb = (vgb - 1.f) *
                    __builtin_amdgcn_rcpf((1.f + uib) * (1.f + vgb));

                const float ca = __builtin_fmaf(sfa, cst[qa][e], pa);
                const float cb = __builtin_fmaf(sfb, cst[qb][e], pb);
                cna[e] = ca; cnb[e] = cb;

                const float uoa = __builtin_amdgcn_exp2f(acc[qa + 12][e]);
                const float uob = __builtin_amdgcn_exp2f(acc[qb + 12][e]);
                const float vca = __builtin_amdgcn_exp2f(fminf(2.8853900817779268f * ca, 43.f));
                const float vcb = __builtin_amdgcn_exp2f(fminf(2.8853900817779268f * cb, 43.f));
                hna[e] = (vca - 1.f) * __builtin_amdgcn_rcpf((1.f + uoa) * (1.f + vca));
                hnb[e] = (vcb - 1.f) * __builtin_amdgcn_rcpf((1.f + uob) * (1.f + vcb));
            }
            cst[qa] = cna; cst[qb] = cnb;
            hvf[qa] = hna; hvf[qb] = hnb;
        }

        // next-step B fragments via packed cvt (RNE), directly as K=32 pairs
        bh01 = __builtin_bit_cast(s16x8,
                   (u32x4){pkbf(hvf[0][0], hvf[0][1]), pkbf(hvf[0][2], hvf[0][3]),
                           pkbf(hvf[1][0], hvf[1][1]), pkbf(hvf[1][2], hvf[1][3])});
        bh23 = __builtin_bit_cast(s16x8,
                   (u32x4){pkbf(hvf[2][0], hvf[2][1]), pkbf(hvf[2][2], hvf[2][3]),
                           pkbf(hvf[3][0], hvf[3][1]), pkbf(hvf[3][2], hvf[3][3])});

        // g_t raw partial; first reduction stage at iter end (stage 2 next iter)
        float gpart = 0.f;
#pragma unroll
        for (int q = 0; q < 4; ++q)
#pragma unroll
            for (int e = 0; e < 4; ++e)
                gpart = __builtin_fmaf(hvf[q][e], wg_l[q][e], gpart);

        // out[t,cell] = gain * softplus(x-1); gain = g_t, 1, g_{t-2}
        const float x1 = xs_cur - 1.f;
        const float sp = fmaxf(x1, 0.f) +
            0.6931471805599453f * __builtin_amdgcn_logf(
                1.f + __builtin_amdgcn_exp2f(-1.4426950408889634f * fabsf(x1)));
        if (t >= 2) {
            const float gain = g2save + bg0;         // = g_{t-2}
            if (g4 == 0) {
                ON[(size_t)t * 16384 + cellbase + c15] = gain * sp;
                if (t == 2) ON[cellbase + c15] = gain * sp0;   // gain_0 = g_0
            }
        } else if (t == 1) {
            if (g4 == 0) ON[(size_t)16384 + cellbase + c15] = sp;  // gain=1
        } else {
            sp0 = sp;                                // ON[0] deferred to t==2
        }
        g2save = s2new;                              // s2 of step t-1
        g_s1 = gpart + __shfl_xor(gpart, 16, 64);    // s1 of step t
    }
}

extern "C" void kernel_launch(void* const* d_in, const int* in_sizes, int n_in,
                              void* d_out, int out_size, void* d_ws, size_t ws_size,
                              hipStream_t stream)
{
    const float* input = (const float*)d_in[0];   // [512][64][128]
    const float* W2n   = (const float*)d_in[1];   // [256][128]
    const float* b2n   = (const float*)d_in[2];   // [256]
    const float* W_ih  = (const float*)d_in[3];   // [256] (4H x 1)
    const float* W_hh  = (const float*)d_in[4];   // [256][64]
    const float* b_ih  = (const float*)d_in[5];   // [256]
    const float* b_hh  = (const float*)d_in[6];   // [256]
    const float* Wg    = (const float*)d_in[7];   // [64]  (1 x H)
    const float* bg    = (const float*)d_in[8];   // [1]
    const float* Wout  = (const float*)d_in[9];   // [64][256]
    const float* bout  = (const float*)d_in[10];  // [64]

    float* x2n = (float*)d_ws;                          // 512*16384 f32 = 32MB
    float* ON  = x2n + (size_t)512 * 16384;             // another 32MB

    // Stage 1: x2n = input @ W2n^T + b2n   (M=32768, N=256, K=128)
    gemm_xwT<<<dim3(512, 4), 256, 0, stream>>>(input, W2n, b2n, x2n, 256, 128);

    // Stage 2: recurrent scan -> ON
    lstm_scan<<<1024, 64, 0, stream>>>(x2n, W_hh, W_ih, b_ih, b_hh, Wg, bg, ON);

    // Stage 3: out = ON @ Wout^T + bout    (M=32768, N=64, K=256)
    gemm_xwT<<<dim3(512, 1), 256, 0, stream>>>(ON, Wout, bout, (float*)d_out, 64, 256);
}